// Round 4
// baseline (360.396 us; speedup 1.0000x reference)
//
#include <hip/hip_runtime.h>
#include <hip/hip_bf16.h>

// ---------------------------------------------------------------------------
// Fully fused: conv encoder (30 imgs) + GRU encoder (30 steps) +
// autoregressive decoder (20 steps) per batch element, one block each.
// B=1024 blocks x 256 threads (4 waves), 4 blocks/CU.
//   conv phase : 8 iters x 4 waves, each wave = one image on a private LDS
//                slice (round-1 algorithm, measured 90us issue-bound).
//   enc/dec    : round-1 4-wave scheme, partials through double-buffered LDS,
//                one barrier/step; enc_in lives in LDS (no global traffic).
// ---------------------------------------------------------------------------

#define B_    1024
#define L_    30
#define H_    64

__device__ __forceinline__ float sigmoid_f(float v) {
    return 1.f / (1.f + __expf(-v));
}
__device__ __forceinline__ float tanh_f(float v) {
    v = fminf(fmaxf(v, -15.f), 15.f);
    float e = __expf(2.f * v);
    return (e - 1.f) / (e + 1.f);
}
__device__ __forceinline__ void load4_lds(float* r, const float* p) {
    float2 a = *(const float2*)p;
    float2 b = *(const float2*)(p + 2);
    r[0] = a.x; r[1] = a.y; r[2] = b.x; r[3] = b.y;
}

__global__ __launch_bounds__(256, 4) void fused_all_kernel(
    const float* __restrict__ bbox,
    const float* __restrict__ head,
    const float* __restrict__ c1w, const float* __restrict__ c1b,
    const float* __restrict__ c2w, const float* __restrict__ c2b,
    const float* __restrict__ fcw, const float* __restrict__ fcb,
    const float* __restrict__ ewih, const float* __restrict__ ewhh,
    const float* __restrict__ ebih, const float* __restrict__ ebhh,
    const float* __restrict__ dwih, const float* __restrict__ dwhh,
    const float* __restrict__ dbih, const float* __restrict__ dbhh,
    const float* __restrict__ linw, const float* __restrict__ linb,
    float* __restrict__ out)
{
    const int b = blockIdx.x;
    const int tid = threadIdx.x;
    const int w = tid >> 6, lane = tid & 63;

    // LDS: [0 .. 9631] = 4x per-wave conv scratch (img 1024 | p1 960 | p2 360 | red 64)
    //      [9632 .. 9901] = enc_s[30][9]
    // GRU sp buffer [2][4][3][64] = 1536 floats aliases conv scratch (conv done).
    __shared__ float smem[9904];
    float* enc_s = smem + 9632;
    float* wb    = smem + w * 2408;
    float* s_img = wb;
    float* s_p1  = wb + 1024;
    float* s_p2  = wb + 1984;
    float* s_red = wb + 2344;
    float* sp    = smem;               // [ (pb*4 + wave)*3 + gate ]*64 + j

    // =================== conv phase: 30 images over 8 iters ================
    for (int it = 0; it < 8; ++it) {
        const int l = it * 4 + w;
        const bool act = (l < L_);

        if (act) {
            const float4* src = (const float4*)(head + ((size_t)b * 31 + (size_t)l) * 1024);
            float4* dst = (float4*)s_img;
            #pragma unroll
            for (int i = 0; i < 4; ++i) dst[lane + 64 * i] = src[lane + 64 * i];
        }
        __syncthreads();

        // stage 1: conv1 + relu + pool; lane = (c, px), rolling 4-row window
        if (act && lane < 60) {
            const int c = lane / 15, px = lane % 15;
            const int x0 = 2 * px;
            float wg[9];
            #pragma unroll
            for (int k = 0; k < 9; ++k) wg[k] = c1w[c * 9 + k];
            const float bias = c1b[c];

            float r0[4], r1[4], r2[4], r3[4];
            load4_lds(r0, s_img + 0 * 32 + x0);
            load4_lds(r1, s_img + 1 * 32 + x0);
            #pragma unroll
            for (int py = 0; py < 15; ++py) {
                load4_lds(r2, s_img + (2 * py + 2) * 32 + x0);
                load4_lds(r3, s_img + (2 * py + 3) * 32 + x0);
                float a00 = bias, a01 = bias, a10 = bias, a11 = bias;
                #pragma unroll
                for (int kx = 0; kx < 3; ++kx) {
                    const float w0 = wg[kx], w1 = wg[3 + kx], w2 = wg[6 + kx];
                    a00 = fmaf(w0, r0[kx],     fmaf(w1, r1[kx],     fmaf(w2, r2[kx],     a00)));
                    a01 = fmaf(w0, r0[kx + 1], fmaf(w1, r1[kx + 1], fmaf(w2, r2[kx + 1], a01)));
                    a10 = fmaf(w0, r1[kx],     fmaf(w1, r2[kx],     fmaf(w2, r3[kx],     a10)));
                    a11 = fmaf(w0, r1[kx + 1], fmaf(w1, r2[kx + 1], fmaf(w2, r3[kx + 1], a11)));
                }
                a00 = fmaxf(a00, 0.f); a01 = fmaxf(a01, 0.f);
                a10 = fmaxf(a10, 0.f); a11 = fmaxf(a11, 0.f);
                s_p1[c * 240 + py * 16 + px] = fmaxf(fmaxf(a00, a01), fmaxf(a10, a11));
                #pragma unroll
                for (int q = 0; q < 4; ++q) { r0[q] = r2[q]; r1[q] = r3[q]; }
            }
        }
        __syncthreads();

        // stage 2: conv2 + relu + pool; lane = (c, px), rolling window
        if (act && lane < 60) {
            const int c = lane / 6, px = lane % 6;
            const int x0 = 2 * px;
            float wg[4][9];
            #pragma unroll
            for (int ic = 0; ic < 4; ++ic)
                #pragma unroll
                for (int k = 0; k < 9; ++k) wg[ic][k] = c2w[(c * 4 + ic) * 9 + k];
            const float bias = c2b[c];

            float win[4][4][4];
            #pragma unroll
            for (int ic = 0; ic < 4; ++ic) {
                load4_lds(win[0][ic], s_p1 + ic * 240 + 0 * 16 + x0);
                load4_lds(win[1][ic], s_p1 + ic * 240 + 1 * 16 + x0);
            }
            #pragma unroll
            for (int py = 0; py < 6; ++py) {
                #pragma unroll
                for (int ic = 0; ic < 4; ++ic) {
                    load4_lds(win[2][ic], s_p1 + ic * 240 + (2 * py + 2) * 16 + x0);
                    load4_lds(win[3][ic], s_p1 + ic * 240 + (2 * py + 3) * 16 + x0);
                }
                float a00 = bias, a01 = bias, a10 = bias, a11 = bias;
                #pragma unroll
                for (int ic = 0; ic < 4; ++ic) {
                    #pragma unroll
                    for (int kx = 0; kx < 3; ++kx) {
                        const float w0 = wg[ic][kx], w1 = wg[ic][3 + kx], w2 = wg[ic][6 + kx];
                        a00 = fmaf(w0, win[0][ic][kx],     fmaf(w1, win[1][ic][kx],     fmaf(w2, win[2][ic][kx],     a00)));
                        a01 = fmaf(w0, win[0][ic][kx + 1], fmaf(w1, win[1][ic][kx + 1], fmaf(w2, win[2][ic][kx + 1], a01)));
                        a10 = fmaf(w0, win[1][ic][kx],     fmaf(w1, win[2][ic][kx],     fmaf(w2, win[3][ic][kx],     a10)));
                        a11 = fmaf(w0, win[1][ic][kx + 1], fmaf(w1, win[2][ic][kx + 1], fmaf(w2, win[3][ic][kx + 1], a11)));
                    }
                }
                a00 = fmaxf(a00, 0.f); a01 = fmaxf(a01, 0.f);
                a10 = fmaxf(a10, 0.f); a11 = fmaxf(a11, 0.f);
                s_p2[c * 36 + py * 6 + px] = fmaxf(fmaxf(a00, a01), fmaxf(a10, a11));
                #pragma unroll
                for (int ic = 0; ic < 4; ++ic)
                    #pragma unroll
                    for (int q = 0; q < 4; ++q) { win[0][ic][q] = win[2][ic][q]; win[1][ic][q] = win[3][ic][q]; }
            }
        }
        __syncthreads();

        // stage 3: fc 360->5 partials
        if (act && lane < 60) {
            const int o = lane / 12, i0 = lane % 12;
            const float* wrow = fcw + o * 360;
            float acc = 0.f;
            #pragma unroll
            for (int k = 0; k < 30; ++k) {
                const int i = i0 + 12 * k;
                acc = fmaf(wrow[i], s_p2[i], acc);
            }
            s_red[lane] = acc;
        }
        __syncthreads();

        if (act) {
            if (lane < 5) {
                float acc = fcb[lane];
                #pragma unroll
                for (int k = 0; k < 12; ++k) acc += s_red[lane * 12 + k];
                enc_s[l * 9 + 4 + lane] = acc;
            } else if (lane >= 8 && lane < 12) {
                const int d = lane - 8;
                const float* bb = bbox + (size_t)b * 124 + (size_t)l * 4;
                enc_s[l * 9 + d] = bb[4 + d] - bb[d];
            }
        }
        // next-iter image load only touches this wave's s_img: no barrier needed
    }
    __syncthreads();   // enc_s complete; conv scratch free for sp reuse

    const int j = lane;
    float h = 0.f;

    // =================== GRU encoder: 30 steps =============================
    {
        float Wh[3][16];
        #pragma unroll
        for (int g = 0; g < 3; ++g) {
            const float4* row = (const float4*)(ewhh + (size_t)(g * 64 + j) * 64 + w * 16);
            #pragma unroll
            for (int k4 = 0; k4 < 4; ++k4) *(float4*)&Wh[g][4 * k4] = row[k4];
        }
        float Wi[3][9];
        #pragma unroll
        for (int g = 0; g < 3; ++g) {
            const float* row = ewih + (g * 64 + j) * 9;
            #pragma unroll
            for (int k = 0; k < 9; ++k) Wi[g][k] = row[k];
        }
        const float bi0 = ebih[j], bi1 = ebih[64 + j], bi2 = ebih[128 + j];
        const float bh0 = ebhh[j], bh1 = ebhh[64 + j], bh2 = ebhh[128 + j];

        for (int t = 0; t < L_; ++t) {
            const int pb = t & 1;
            float pr = 0.f, pz = 0.f, pn = 0.f;
            #pragma unroll
            for (int k = 0; k < 16; ++k) {
                const float hk = __shfl(h, w * 16 + k);
                pr = fmaf(Wh[0][k], hk, pr);
                pz = fmaf(Wh[1][k], hk, pz);
                pn = fmaf(Wh[2][k], hk, pn);
            }
            sp[((pb * 4 + w) * 3 + 0) * 64 + j] = pr;
            sp[((pb * 4 + w) * 3 + 1) * 64 + j] = pz;
            sp[((pb * 4 + w) * 3 + 2) * 64 + j] = pn;

            float gr = bi0 + bh0, gz = bi1 + bh1, gni = bi2, gnh = bh2;
            #pragma unroll
            for (int k = 0; k < 9; ++k) {
                const float xk = enc_s[t * 9 + k];
                gr  = fmaf(Wi[0][k], xk, gr);
                gz  = fmaf(Wi[1][k], xk, gz);
                gni = fmaf(Wi[2][k], xk, gni);
            }
            __syncthreads();
            #pragma unroll
            for (int ww = 0; ww < 4; ++ww) {
                gr  += sp[((pb * 4 + ww) * 3 + 0) * 64 + j];
                gz  += sp[((pb * 4 + ww) * 3 + 1) * 64 + j];
                gnh += sp[((pb * 4 + ww) * 3 + 2) * 64 + j];
            }
            const float r = sigmoid_f(gr);
            const float z = sigmoid_f(gz);
            const float n = tanh_f(gni + r * gnh);
            h = (1.f - z) * n + z * h;   // h replicated in all 4 waves
        }
    }

    // =================== decoder: 20 steps + lin + cumsum ==================
    {
        float Wh[3][16];
        #pragma unroll
        for (int g = 0; g < 3; ++g) {
            const float4* row = (const float4*)(dwhh + (size_t)(g * 64 + j) * 64 + w * 16);
            #pragma unroll
            for (int k4 = 0; k4 < 4; ++k4) *(float4*)&Wh[g][4 * k4] = row[k4];
        }
        float Wi[3][4];
        #pragma unroll
        for (int g = 0; g < 3; ++g) {
            const float* row = dwih + (g * 64 + j) * 4;
            #pragma unroll
            for (int k = 0; k < 4; ++k) Wi[g][k] = row[k];
        }
        const float bi0 = dbih[j], bi1 = dbih[64 + j], bi2 = dbih[128 + j];
        const float bh0 = dbhh[j], bh1 = dbhh[64 + j], bh2 = dbhh[128 + j];
        const float lw0 = linw[j], lw1 = linw[64 + j], lw2 = linw[128 + j], lw3 = linw[192 + j];
        const float lb0 = linb[0], lb1 = linb[1], lb2 = linb[2], lb3 = linb[3];

        const float* bb = bbox + (size_t)b * 124;
        float px0 = bb[120] - bb[116];
        float px1 = bb[121] - bb[117];
        float px2 = bb[122] - bb[118];
        float px3 = bb[123] - bb[119];
        const float of0 = bb[120], of1 = bb[121], of2 = bb[122], of3 = bb[123];
        float cs0 = 0.f, cs1 = 0.f, cs2 = 0.f, cs3 = 0.f;
        float4* outp = (float4*)(out + (size_t)b * 80);

        for (int t = 0; t < 20; ++t) {
            const int pb = t & 1;
            float pr = 0.f, pz = 0.f, pn = 0.f;
            #pragma unroll
            for (int k = 0; k < 16; ++k) {
                const float hk = __shfl(h, w * 16 + k);
                pr = fmaf(Wh[0][k], hk, pr);
                pz = fmaf(Wh[1][k], hk, pz);
                pn = fmaf(Wh[2][k], hk, pn);
            }
            sp[((pb * 4 + w) * 3 + 0) * 64 + j] = pr;
            sp[((pb * 4 + w) * 3 + 1) * 64 + j] = pz;
            sp[((pb * 4 + w) * 3 + 2) * 64 + j] = pn;

            float gr = bi0 + bh0, gz = bi1 + bh1, gni = bi2, gnh = bh2;
            gr  = fmaf(Wi[0][0], px0, fmaf(Wi[0][1], px1, fmaf(Wi[0][2], px2, fmaf(Wi[0][3], px3, gr))));
            gz  = fmaf(Wi[1][0], px0, fmaf(Wi[1][1], px1, fmaf(Wi[1][2], px2, fmaf(Wi[1][3], px3, gz))));
            gni = fmaf(Wi[2][0], px0, fmaf(Wi[2][1], px1, fmaf(Wi[2][2], px2, fmaf(Wi[2][3], px3, gni))));

            __syncthreads();
            #pragma unroll
            for (int ww = 0; ww < 4; ++ww) {
                gr  += sp[((pb * 4 + ww) * 3 + 0) * 64 + j];
                gz  += sp[((pb * 4 + ww) * 3 + 1) * 64 + j];
                gnh += sp[((pb * 4 + ww) * 3 + 2) * 64 + j];
            }
            const float r = sigmoid_f(gr);
            const float z = sigmoid_f(gz);
            const float n = tanh_f(gni + r * gnh);
            h = (1.f - z) * n + z * h;

            float v0 = lw0 * h, v1 = lw1 * h, v2 = lw2 * h, v3 = lw3 * h;
            #pragma unroll
            for (int s = 32; s > 0; s >>= 1) {
                v0 += __shfl_xor(v0, s);
                v1 += __shfl_xor(v1, s);
                v2 += __shfl_xor(v2, s);
                v3 += __shfl_xor(v3, s);
            }
            px0 = v0 + lb0 + px0;
            px1 = v1 + lb1 + px1;
            px2 = v2 + lb2 + px2;
            px3 = v3 + lb3 + px3;
            cs0 += px0; cs1 += px1; cs2 += px2; cs3 += px3;
            if (tid == 0) outp[t] = make_float4(cs0 + of0, cs1 + of1, cs2 + of2, cs3 + of3);
        }
    }
}

// ---------------------------------------------------------------------------
extern "C" void kernel_launch(void* const* d_in, const int* in_sizes, int n_in,
                              void* d_out, int out_size, void* d_ws, size_t ws_size,
                              hipStream_t stream) {
    (void)in_sizes; (void)n_in; (void)out_size; (void)d_ws; (void)ws_size;
    const float* bbox = (const float*)d_in[0];
    const float* head = (const float*)d_in[1];
    const float* c1w  = (const float*)d_in[2];
    const float* c1b  = (const float*)d_in[3];
    const float* c2w  = (const float*)d_in[4];
    const float* c2b  = (const float*)d_in[5];
    const float* fcw  = (const float*)d_in[6];
    const float* fcb  = (const float*)d_in[7];
    const float* ewih = (const float*)d_in[8];
    const float* ewhh = (const float*)d_in[9];
    const float* ebih = (const float*)d_in[10];
    const float* ebhh = (const float*)d_in[11];
    const float* dwih = (const float*)d_in[12];
    const float* dwhh = (const float*)d_in[13];
    const float* dbih = (const float*)d_in[14];
    const float* dbhh = (const float*)d_in[15];
    const float* linw = (const float*)d_in[16];
    const float* linb = (const float*)d_in[17];
    float* out = (float*)d_out;

    fused_all_kernel<<<B_, 256, 0, stream>>>(bbox, head, c1w, c1b, c2w, c2b,
                                             fcw, fcb, ewih, ewhh, ebih, ebhh,
                                             dwih, dwhh, dbih, dbhh, linw, linb,
                                             out);
}